// Round 11
// baseline (19.278 us; speedup 1.0000x reference)
//
#include <hip/hip_runtime.h>

// Problem constants (from reference setup_inputs)
#define BB 4
#define LL 8192
#define DD 1024
#define MAXC (LL / 4)   // 2048

typedef float f32x4 __attribute__((ext_vector_type(4)));
typedef int   i32x4 __attribute__((ext_vector_type(4)));

// ---------------------------------------------------------------------------
// Kernel 1: per-batch boundary scan (R5-exact champion version).
// One block of 1024 threads per batch, 8 mask elements per thread.
// Wave-level shuffle scan + single LDS round for 16 wave sums.
// Semantics replicate: argsort(i + (~mask)*L)[:MAXC]
//   = boundary positions in index order, then non-boundary positions in
//     index order (all token_idx values distinct, so order is exact).
// ---------------------------------------------------------------------------
__global__ __launch_bounds__(1024) void chunk_scan_kernel(
    const int* __restrict__ mask,     // [BB][LL] 0/1
    int*       __restrict__ tk_int,   // ws: [BB][MAXC]
    int*       __restrict__ nchunks,  // ws: [BB]
    float*     __restrict__ out_pad,  // [BB][MAXC]
    float*     __restrict__ out_tk)   // [BB][MAXC]
{
    const int b = blockIdx.x;
    const int t = threadIdx.x;
    constexpr int PER = LL / 1024;    // 8

    const int* m = mask + (size_t)b * LL;
    const i32x4* m4 = reinterpret_cast<const i32x4*>(m + t * PER);
    i32x4 v0 = m4[0];
    i32x4 v1 = m4[1];
    int local[PER] = {v0.x, v0.y, v0.z, v0.w, v1.x, v1.y, v1.z, v1.w};

    int s = 0;
#pragma unroll
    for (int j = 0; j < PER; ++j) s += local[j];

    // Wave-level inclusive scan of per-thread sums (wave = 64 lanes).
    const int lane = t & 63;
    const int wid  = t >> 6;          // 16 waves
    int inc = s;
#pragma unroll
    for (int off = 1; off < 64; off <<= 1) {
        int n = __shfl_up(inc, off, 64);
        if (lane >= off) inc += n;
    }

    __shared__ int wsum[16];
    if (lane == 63) wsum[wid] = inc;
    __syncthreads();

    int wpre = 0, total = 0;
#pragma unroll
    for (int w = 0; w < 16; ++w) {    // broadcast reads, no conflicts
        int x = wsum[w];
        total += x;
        wpre += (w < wid) ? x : 0;
    }
    const int excl = wpre + inc - s;              // exclusive prefix (block)
    const int nc   = (total < MAXC) ? total : MAXC;

    // Assign each position its sorted rank and scatter.
    int pb = excl;                    // #boundary strictly before i
    const int base = t * PER;
#pragma unroll
    for (int j = 0; j < PER; ++j) {
        const int i = base + j;
        const int r = local[j] ? pb : (total + (i - pb));
        pb += local[j];
        if (r < MAXC) {
            const int o = b * MAXC + r;
            tk_int[o]  = i;
            out_tk[o]  = (float)i;    // exact: i < 2^24
            out_pad[o] = (r < nc) ? 1.0f : 0.0f;
        }
    }
    if (t == 0) nchunks[b] = nc;
}

// ---------------------------------------------------------------------------
// Kernel 2: gather rows. 4096 blocks x 256 threads; each block copies TWO
// consecutive output rows (2 x 4 KB): shorter per-block critical path and a
// finer dispatch tail than the 4-row champion, identical traffic and cache
// policy (cached loads — read set half-L3-resident, R7 FETCH evidence;
// nontemporal stores — plain stores evict hs from L2, R6).
// ---------------------------------------------------------------------------
__global__ __launch_bounds__(256) void chunk_gather_kernel(
    const float* __restrict__ hs,       // [BB][LL][DD]
    const int*   __restrict__ tk_int,   // [BB][MAXC]
    const int*   __restrict__ nchunks,  // [BB]
    float*       __restrict__ out)      // [BB][MAXC][DD]
{
    const int t    = threadIdx.x;
    const int row0 = blockIdx.x * 2;    // 2 rows per block, same batch
    const int b    = row0 >> 11;        // / MAXC (2048)
    const int nc   = nchunks[b];

    f32x4 vals[2];
#pragma unroll
    for (int k = 0; k < 2; ++k) {
        const int row = row0 + k;
        const int r   = row & (MAXC - 1);
        if (r < nc) {
            const int i = tk_int[row];
            const f32x4* src =
                reinterpret_cast<const f32x4*>(hs + ((size_t)b * LL + i) * DD);
            vals[k] = src[t];                       // cached load
        } else {
            vals[k] = (f32x4){0.f, 0.f, 0.f, 0.f};
        }
    }

    f32x4* o = reinterpret_cast<f32x4*>(out + (size_t)row0 * DD);
#pragma unroll
    for (int k = 0; k < 2; ++k) {
        __builtin_nontemporal_store(vals[k], &o[k * 256 + t]);
    }
}

extern "C" void kernel_launch(void* const* d_in, const int* in_sizes, int n_in,
                              void* d_out, int out_size, void* d_ws, size_t ws_size,
                              hipStream_t stream) {
    const float* hs   = (const float*)d_in[0];   // [4][8192][1024] f32
    const int*   mask = (const int*)d_in[1];     // [4][8192] int (bool 0/1)

    float* out = (float*)d_out;
    float* out_chunk = out;                          // [4][2048][1024]
    float* out_pad   = out + (size_t)BB * MAXC * DD; // [4][2048]
    float* out_tk    = out_pad + (size_t)BB * MAXC;  // [4][2048]

    int* tk_int  = (int*)d_ws;                       // [4][2048]
    int* nchunks = tk_int + BB * MAXC;               // [4]

    chunk_scan_kernel<<<BB, 1024, 0, stream>>>(mask, tk_int, nchunks,
                                               out_pad, out_tk);
    chunk_gather_kernel<<<BB * MAXC / 2, 256, 0, stream>>>(hs, tk_int, nchunks,
                                                           out_chunk);
}

// Round 12
// 18.759 us; speedup vs baseline: 1.0277x; 1.0277x over previous
//
#include <hip/hip_runtime.h>

// Problem constants (from reference setup_inputs)
#define BB 4
#define LL 8192
#define DD 1024
#define MAXC (LL / 4)   // 2048

typedef float f32x4 __attribute__((ext_vector_type(4)));
typedef int   i32x4 __attribute__((ext_vector_type(4)));

// ---------------------------------------------------------------------------
// R5 champion configuration (18.5 us), restored after the full A/B sweep:
//   gather rows/block: 2=19.3, 4=18.5, 8=19.5..23.4
//   cache policy: cached loads (NT loads +2.4us), NT stores (plain +5us)
//   fusion variants: +4..+420us; slim scan: neutral.
// ---------------------------------------------------------------------------

// ---------------------------------------------------------------------------
// Kernel 1: per-batch boundary scan -> ranks -> take_idx / pad_mask.
// One block of 1024 threads per batch, 8 mask elements per thread.
// Wave-level shuffle scan + single LDS round for 16 wave sums.
// Semantics replicate: argsort(i + (~mask)*L)[:MAXC]
//   = boundary positions in index order, then non-boundary positions in
//     index order (all token_idx values distinct, so order is exact).
// ---------------------------------------------------------------------------
__global__ __launch_bounds__(1024) void chunk_scan_kernel(
    const int* __restrict__ mask,     // [BB][LL] 0/1
    int*       __restrict__ tk_int,   // ws: [BB][MAXC]
    int*       __restrict__ nchunks,  // ws: [BB]
    float*     __restrict__ out_pad,  // [BB][MAXC]
    float*     __restrict__ out_tk)   // [BB][MAXC]
{
    const int b = blockIdx.x;
    const int t = threadIdx.x;
    constexpr int PER = LL / 1024;    // 8

    const int* m = mask + (size_t)b * LL;
    const i32x4* m4 = reinterpret_cast<const i32x4*>(m + t * PER);
    i32x4 v0 = m4[0];
    i32x4 v1 = m4[1];
    int local[PER] = {v0.x, v0.y, v0.z, v0.w, v1.x, v1.y, v1.z, v1.w};

    int s = 0;
#pragma unroll
    for (int j = 0; j < PER; ++j) s += local[j];

    // Wave-level inclusive scan of per-thread sums (wave = 64 lanes).
    const int lane = t & 63;
    const int wid  = t >> 6;          // 16 waves
    int inc = s;
#pragma unroll
    for (int off = 1; off < 64; off <<= 1) {
        int n = __shfl_up(inc, off, 64);
        if (lane >= off) inc += n;
    }

    __shared__ int wsum[16];
    if (lane == 63) wsum[wid] = inc;
    __syncthreads();

    int wpre = 0, total = 0;
#pragma unroll
    for (int w = 0; w < 16; ++w) {    // broadcast reads, no conflicts
        int x = wsum[w];
        total += x;
        wpre += (w < wid) ? x : 0;
    }
    const int excl = wpre + inc - s;              // exclusive prefix (block)
    const int nc   = (total < MAXC) ? total : MAXC;

    // Assign each position its sorted rank and scatter.
    int pb = excl;                    // #boundary strictly before i
    const int base = t * PER;
#pragma unroll
    for (int j = 0; j < PER; ++j) {
        const int i = base + j;
        const int r = local[j] ? pb : (total + (i - pb));
        pb += local[j];
        if (r < MAXC) {
            const int o = b * MAXC + r;
            tk_int[o]  = i;
            out_tk[o]  = (float)i;    // exact: i < 2^24
            out_pad[o] = (r < nc) ? 1.0f : 0.0f;
        }
    }
    if (t == 0) nchunks[b] = nc;
}

// ---------------------------------------------------------------------------
// Kernel 2: gather rows. 2048 blocks x 256 threads; each block copies FOUR
// consecutive output rows (4 x 4 KB). Cached loads (read set ~half
// L3-resident across replays), nontemporal stores (write-once stream must
// not evict the hs read set from L2).
// ---------------------------------------------------------------------------
__global__ __launch_bounds__(256) void chunk_gather_kernel(
    const float* __restrict__ hs,       // [BB][LL][DD]
    const int*   __restrict__ tk_int,   // [BB][MAXC]
    const int*   __restrict__ nchunks,  // [BB]
    float*       __restrict__ out)      // [BB][MAXC][DD]
{
    const int t    = threadIdx.x;
    const int row0 = blockIdx.x * 4;    // 4 rows per block, same batch
    const int b    = row0 >> 11;        // / MAXC (2048)
    const int nc   = nchunks[b];

    f32x4 vals[4];
#pragma unroll
    for (int k = 0; k < 4; ++k) {
        const int row = row0 + k;
        const int r   = row & (MAXC - 1);
        if (r < nc) {
            const int i = tk_int[row];
            const f32x4* src =
                reinterpret_cast<const f32x4*>(hs + ((size_t)b * LL + i) * DD);
            vals[k] = src[t];                       // cached load
        } else {
            vals[k] = (f32x4){0.f, 0.f, 0.f, 0.f};
        }
    }

    f32x4* o = reinterpret_cast<f32x4*>(out + (size_t)row0 * DD);
#pragma unroll
    for (int k = 0; k < 4; ++k) {
        __builtin_nontemporal_store(vals[k], &o[k * 256 + t]);
    }
}

extern "C" void kernel_launch(void* const* d_in, const int* in_sizes, int n_in,
                              void* d_out, int out_size, void* d_ws, size_t ws_size,
                              hipStream_t stream) {
    const float* hs   = (const float*)d_in[0];   // [4][8192][1024] f32
    const int*   mask = (const int*)d_in[1];     // [4][8192] int (bool 0/1)

    float* out = (float*)d_out;
    float* out_chunk = out;                          // [4][2048][1024]
    float* out_pad   = out + (size_t)BB * MAXC * DD; // [4][2048]
    float* out_tk    = out_pad + (size_t)BB * MAXC;  // [4][2048]

    int* tk_int  = (int*)d_ws;                       // [4][2048]
    int* nchunks = tk_int + BB * MAXC;               // [4]

    chunk_scan_kernel<<<BB, 1024, 0, stream>>>(mask, tk_int, nchunks,
                                               out_pad, out_tk);
    chunk_gather_kernel<<<BB * MAXC / 4, 256, 0, stream>>>(hs, tk_int, nchunks,
                                                           out_chunk);
}